// Round 1
// baseline (447.671 us; speedup 1.0000x reference)
//
#include <hip/hip_runtime.h>

// =====================================================================
// QuadraticChargesEnergyReadout — algebraic collapse:
//   s[n,:]   = a*As + b*Bs + c          (a=si, b=s0 per-node scalars)
//   v[n,:,i] = g_i*Av + d_i*Bv
// All quadratic forms against W_ss/W_vv/W_sv/W_vs reduce to 15 per-w
// coefficients; folding through Wd_s/Wd_v gives 15 fixed 128-vectors.
// energy[n] = sum_f nf_s[n,f] * (9-monomial combo of Ms[f][0..8])
//           + sum_{f,i} nf_v[n,f,i] * (g_i*Wg[f] + d_i*Wd[f])
//   with Wg[f] = a*Mv0+b*Mv2+Mv4, Wd[f] = a*Mv1+b*Mv3+Mv5.
// Memory-bound: ~274 MB traffic, roofline ~43 us.
// =====================================================================

#define TBLK 128          // threads per block == nodes per block
#define NNODES 131072

// ---------------- precompute 1: per-w quadratic-form coefficients -----
// coeff[k*32+w]: k 0..5 = P (s.s vs W_ss), 6..8 = Q (v.v vs W_vv),
//                9..14 = K (s.v vs W_sv + v.s vs W_vs)
__global__ void precompute_coeff(
    const float* __restrict__ Wa_s, const float* __restrict__ Wa_v,
    const float* __restrict__ b_a,  const float* __restrict__ Wb_s,
    const float* __restrict__ Wb_v, const float* __restrict__ b_b,
    const float* __restrict__ W_ss, const float* __restrict__ W_vv,
    const float* __restrict__ W_sv, const float* __restrict__ W_vs,
    float* __restrict__ coeff)
{
  __shared__ float As[32], Bs[32], Cc[32], Av[32], Bv[32];
  const int t = threadIdx.x;                     // 256 threads, 32 blocks
  if (t < 32) {
    As[t] = Wa_s[t]; Bs[t] = Wb_s[t]; Cc[t] = b_a[t] + b_b[t];
    Av[t] = Wa_v[t]; Bv[t] = Wb_v[t];
  }
  __syncthreads();
  const int w = t & 31;                          // lanes differ in w -> coalesced
  const int chunk = blockIdx.x * 8 + (t >> 5);   // 256 chunks x 4 pairs = 1024 (u,v)
  float acc[15];
  #pragma unroll
  for (int k = 0; k < 15; ++k) acc[k] = 0.f;
  #pragma unroll
  for (int j = 0; j < 4; ++j) {
    const int p = chunk * 4 + j;                 // pair index = u*32+v
    const int u = p >> 5, v = p & 31;
    const float wss = W_ss[p * 32 + w];
    const float wvv = W_vv[p * 32 + w];
    const float wsv = W_sv[p * 32 + w];
    const float wvs = W_vs[p * 32 + w];
    const float au = As[u], bu = Bs[u], cu = Cc[u], pu = Av[u], qu = Bv[u];
    const float av = As[v], bv = Bs[v], cv = Cc[v], pv = Av[v], qv = Bv[v];
    acc[0]  = fmaf(au * av, wss, acc[0]);                    // a^2
    acc[1]  = fmaf(au * bv + bu * av, wss, acc[1]);          // a*b
    acc[2]  = fmaf(bu * bv, wss, acc[2]);                    // b^2
    acc[3]  = fmaf(au * cv + cu * av, wss, acc[3]);          // a
    acc[4]  = fmaf(bu * cv + cu * bv, wss, acc[4]);          // b
    acc[5]  = fmaf(cu * cv, wss, acc[5]);                    // 1
    acc[6]  = fmaf(pu * pv, wvv, acc[6]);                    // sum g^2
    acc[7]  = fmaf(pu * qv + qu * pv, wvv, acc[7]);          // sum g*d
    acc[8]  = fmaf(qu * qv, wvv, acc[8]);                    // sum d^2
    acc[9]  = fmaf(au * pv, wsv, fmaf(pu * av, wvs, acc[9]));   // a*g_i
    acc[10] = fmaf(au * qv, wsv, fmaf(qu * av, wvs, acc[10]));  // a*d_i
    acc[11] = fmaf(bu * pv, wsv, fmaf(pu * bv, wvs, acc[11]));  // b*g_i
    acc[12] = fmaf(bu * qv, wsv, fmaf(qu * bv, wvs, acc[12]));  // b*d_i
    acc[13] = fmaf(cu * pv, wsv, fmaf(pu * cv, wvs, acc[13]));  // g_i
    acc[14] = fmaf(cu * qv, wsv, fmaf(qu * cv, wvs, acc[14]));  // d_i
  }
  #pragma unroll
  for (int k = 0; k < 15; ++k) atomicAdd(&coeff[k * 32 + w], acc[k]);
}

// ---------------- precompute 2: fold through Wd_s / Wd_v --------------
// Ms[f*16+k] (k=0..8), Mv[f*8+k] (k=0..5); scales baked in.
__global__ void precompute_M(
    const float* __restrict__ Wd_s, const float* __restrict__ Wd_v,
    const float* __restrict__ coeff,
    float* __restrict__ Ms, float* __restrict__ Mv)
{
  const int f = threadIdx.x;                    // 128 threads, 1 block
  float as[9], av[6];
  #pragma unroll
  for (int k = 0; k < 9; ++k) as[k] = 0.f;
  #pragma unroll
  for (int k = 0; k < 6; ++k) av[k] = 0.f;
  for (int w = 0; w < 32; ++w) {
    const float wds = Wd_s[w * 128 + f];
    const float wdv = Wd_v[w * 128 + f];
    #pragma unroll
    for (int k = 0; k < 9; ++k) as[k] = fmaf(coeff[k * 32 + w], wds, as[k]);
    #pragma unroll
    for (int k = 0; k < 6; ++k) av[k] = fmaf(coeff[(9 + k) * 32 + w], wdv, av[k]);
  }
  // PW_DOWN*PW_QQ_S = sqrt(1/(8192*2048)) = 1/4096 exactly.
  // Q terms get extra INV_SQRT3; v terms: PW_DOWN*PW_QQ_V/3 = INV_SQRT3/4096.
  const float sP = 1.0f / 4096.0f;
  const float sQ = 0.57735026918962576451f / 4096.0f;
  #pragma unroll
  for (int k = 0; k < 6; ++k) Ms[f * 16 + k] = as[k] * sP;
  #pragma unroll
  for (int k = 0; k < 3; ++k) Ms[f * 16 + 6 + k] = as[6 + k] * sQ;
  #pragma unroll
  for (int k = 0; k < 6; ++k) Mv[f * 8 + k] = av[k] * sQ;
}

// ---------------- main kernel ----------------------------------------
__device__ __forceinline__ float wcomb9(const float* __restrict__ p,
    float m0, float m1, float m2, float a, float b,
    float m6, float m7, float m8)
{
  float r = p[5];
  r = fmaf(m0, p[0], r);
  r = fmaf(m1, p[1], r);
  r = fmaf(m2, p[2], r);
  r = fmaf(a,  p[3], r);
  r = fmaf(b,  p[4], r);
  r = fmaf(m6, p[6], r);
  r = fmaf(m7, p[7], r);
  r = fmaf(m8, p[8], r);
  return r;
}

// v-region tile: 64 columns starting at cc_base = 3*qb + PHASE (cc = col-128).
// f = qb + (PHASE+l)/3, i = (PHASE+l)%3 fold to compile-time after unroll.
template<int PHASE>
__device__ __forceinline__ void vtile_compute(
    const float4* __restrict__ tile4, const int t, const int swz, const int qb,
    const float* __restrict__ Mv,
    const float alpha, const float beta,
    const float g0, const float g1, const float g2,
    const float d0, const float d1, const float d2,
    float& e0, float& e1, float& e2, float& e3)
{
  #pragma unroll
  for (int j4 = 0; j4 < 16; ++j4) {
    const float4 x = tile4[t * 16 + (j4 ^ swz)];
    const float xs[4] = {x.x, x.y, x.z, x.w};
    #pragma unroll
    for (int e = 0; e < 4; ++e) {
      const int l = 4 * j4 + e;
      const int i = (PHASE + l) % 3;
      const int f = qb + (PHASE + l) / 3;
      const float* cv = Mv + f * 8;                 // lane-uniform -> s_load
      const float Wg = fmaf(alpha, cv[0], fmaf(beta, cv[2], cv[4]));
      const float Wd = fmaf(alpha, cv[1], fmaf(beta, cv[3], cv[5]));
      const float gs = (i == 0) ? g0 : ((i == 1) ? g1 : g2);
      const float ds = (i == 0) ? d0 : ((i == 1) ? d1 : d2);
      const float wv = fmaf(gs, Wg, ds * Wd);
      if      (e == 0) e0 = fmaf(xs[0], wv, e0);
      else if (e == 1) e1 = fmaf(xs[1], wv, e1);
      else if (e == 2) e2 = fmaf(xs[2], wv, e2);
      else             e3 = fmaf(xs[3], wv, e3);
    }
  }
}

__global__ __launch_bounds__(TBLK, 2) void energy_main(
    const float* __restrict__ nf,
    const float* __restrict__ ch0,
    const float* __restrict__ chi,
    const float* __restrict__ Ms,
    const float* __restrict__ Mv,
    float* __restrict__ out)
{
  // 128 rows x 16 float4 groups, XOR-swizzled: group g of row r at slot
  // g^(r&15) -> conflict-free b128 in both staging and per-thread read.
  __shared__ float4 tile4[TBLK * 16];               // 32 KB -> 4 blocks/CU
  const int t = threadIdx.x;
  const int node0 = blockIdx.x * TBLK;

  const float4 cc0 = reinterpret_cast<const float4*>(ch0)[node0 + t];
  const float4 cci = reinterpret_cast<const float4*>(chi)[node0 + t];
  const float alpha = cci.x, g0 = cci.y, g1 = cci.z, g2 = cci.w;
  const float beta  = cc0.x, d0 = cc0.y, d1 = cc0.z, d2 = cc0.w;
  const float m0 = alpha * alpha, m1 = alpha * beta, m2 = beta * beta;
  const float m6 = fmaf(g0, g0, fmaf(g1, g1, g2 * g2));
  const float m7 = fmaf(g0, d0, fmaf(g1, d1, g2 * d2));
  const float m8 = fmaf(d0, d0, fmaf(d1, d1, d2 * d2));

  const int lr = t >> 4;        // row subgroup 0..7
  const int lc = t & 15;        // float4 slot within row
  const int swz = t & 15;

  float e0 = 0.f, e1 = 0.f, e2 = 0.f, e3 = 0.f;

  for (int tl = 0; tl < 8; ++tl) {                  // 8 tiles x 64 cols
    __syncthreads();                                // protect prior reads
    const float* gsrc = nf + (size_t)node0 * 512 + tl * 64;
    #pragma unroll
    for (int p = 0; p < 16; ++p) {                  // stage 128 rows x 64 cols
      const int row = p * 8 + lr;
      const float4 v = reinterpret_cast<const float4*>(gsrc + (size_t)row * 512)[lc];
      tile4[row * 16 + (lc ^ (row & 15))] = v;
    }
    __syncthreads();

    if (tl < 2) {                                   // s-region: cols 0..127
      const int fbase = tl * 64;
      #pragma unroll
      for (int j4 = 0; j4 < 16; ++j4) {
        const float4 x = tile4[t * 16 + (j4 ^ swz)];
        const float* cp = Ms + (fbase + 4 * j4) * 16;   // lane-uniform
        e0 = fmaf(x.x, wcomb9(cp,      m0, m1, m2, alpha, beta, m6, m7, m8), e0);
        e1 = fmaf(x.y, wcomb9(cp + 16, m0, m1, m2, alpha, beta, m6, m7, m8), e1);
        e2 = fmaf(x.z, wcomb9(cp + 32, m0, m1, m2, alpha, beta, m6, m7, m8), e2);
        e3 = fmaf(x.w, wcomb9(cp + 48, m0, m1, m2, alpha, beta, m6, m7, m8), e3);
      }
    } else {                                        // v-region: cols 128..511
      const int k = tl - 2;
      const int qb = (k * 64) / 3;                  // cc_base = 64k = 3*qb + (k%3)
      switch (k % 3) {
        case 0: vtile_compute<0>(tile4, t, swz, qb, Mv, alpha, beta, g0, g1, g2, d0, d1, d2, e0, e1, e2, e3); break;
        case 1: vtile_compute<1>(tile4, t, swz, qb, Mv, alpha, beta, g0, g1, g2, d0, d1, d2, e0, e1, e2, e3); break;
        default: vtile_compute<2>(tile4, t, swz, qb, Mv, alpha, beta, g0, g1, g2, d0, d1, d2, e0, e1, e2, e3); break;
      }
    }
  }
  out[node0 + t] = (e0 + e1) + (e2 + e3);
}

// ---------------- launcher -------------------------------------------
extern "C" void kernel_launch(void* const* d_in, const int* in_sizes, int n_in,
                              void* d_out, int out_size, void* d_ws, size_t ws_size,
                              hipStream_t stream)
{
  const float* node_feats      = (const float*)d_in[0];
  const float* charges_0       = (const float*)d_in[1];
  const float* charges_induced = (const float*)d_in[2];
  const float* Wa_s = (const float*)d_in[8];
  const float* Wa_v = (const float*)d_in[9];
  const float* b_a  = (const float*)d_in[10];
  const float* Wb_s = (const float*)d_in[11];
  const float* Wb_v = (const float*)d_in[12];
  const float* b_b  = (const float*)d_in[13];
  const float* W_ss = (const float*)d_in[14];
  const float* W_vv = (const float*)d_in[15];
  const float* W_sv = (const float*)d_in[16];
  const float* W_vs = (const float*)d_in[17];
  const float* Wd_s = (const float*)d_in[18];
  const float* Wd_v = (const float*)d_in[19];

  float* ws    = (float*)d_ws;
  float* Ms    = ws;            // [128][16] = 2048 floats
  float* Mv    = ws + 2048;     // [128][8]  = 1024 floats
  float* coeff = ws + 3072;     // [15][32]  = 480 floats

  hipMemsetAsync(coeff, 0, 480 * sizeof(float), stream);
  precompute_coeff<<<32, 256, 0, stream>>>(Wa_s, Wa_v, b_a, Wb_s, Wb_v, b_b,
                                           W_ss, W_vv, W_sv, W_vs, coeff);
  precompute_M<<<1, 128, 0, stream>>>(Wd_s, Wd_v, coeff, Ms, Mv);
  energy_main<<<NNODES / TBLK, TBLK, 0, stream>>>(node_feats, charges_0,
                                                  charges_induced, Ms, Mv,
                                                  (float*)d_out);
}

// Round 3
// 434.546 us; speedup vs baseline: 1.0302x; 1.0302x over previous
//
#include <hip/hip_runtime.h>

// =====================================================================
// QuadraticChargesEnergyReadout — algebraic collapse (see R1):
//   s[n,:]   = a*As + b*Bs + c          (a=si, b=s0 per-node scalars)
//   v[n,:,i] = g_i*Av + d_i*Bv
// 15 precomputed coefficient 128-vectors (Ms 9, Mv 6); per node the
// energy is a weighted dot of its 512 feats against lane-uniform
// (s_load) combinations of these vectors.
// R3: R2 + explicit s_waitcnt(0) before every __syncthreads(). R2's
// single-barrier double-buffer raced: the compiler is not obliged to
// drain lgkmcnt for ds_READS at a barrier (no cross-wave visibility),
// so warm-latency DMA overwrote a buffer while prior-iter ds_reads
// were still in flight (cold call passed, warm calls deterministically
// wrong). The explicit full drain closes the WAR and RAW windows.
// Memory-bound: ~274 MB traffic, roofline ~43 us.
// =====================================================================

#define TBLK 128
#define NNODES 131072

// ---------- async global->LDS (16 B/lane, lane-contiguous LDS dest) ----
typedef __attribute__((address_space(1))) const void gas_void;
typedef __attribute__((address_space(3))) void las_void;
__device__ __forceinline__ void gl_lds16(const void* g, void* l) {
  __builtin_amdgcn_global_load_lds((gas_void*)g, (las_void*)l, 16, 0, 0);
}

// ---------------- precompute 1: per-block partial coefficients --------
// partial[b][k][w], k 0..5 = s.s monomials {a2,ab,b2,a,b,1} vs W_ss,
// 6..8 = {Sg2,Sgd,Sd2} vs W_vv, 9..14 = {ag,ad,bg,bd,g,d} vs W_sv/W_vs.
__global__ void precompute_coeff(
    const float* __restrict__ Wa_s, const float* __restrict__ Wa_v,
    const float* __restrict__ b_a,  const float* __restrict__ Wb_s,
    const float* __restrict__ Wb_v, const float* __restrict__ b_b,
    const float* __restrict__ W_ss, const float* __restrict__ W_vv,
    const float* __restrict__ W_sv, const float* __restrict__ W_vs,
    float* __restrict__ partial)
{
  __shared__ float As[32], Bs[32], Cc[32], Avv[32], Bvv[32];
  __shared__ float red[8][480];
  const int t = threadIdx.x;                     // 256 threads, 32 blocks
  if (t < 32) {
    As[t] = Wa_s[t]; Bs[t] = Wb_s[t]; Cc[t] = b_a[t] + b_b[t];
    Avv[t] = Wa_v[t]; Bvv[t] = Wb_v[t];
  }
  __syncthreads();
  const int w = t & 31;
  const int grp = t >> 5;
  const int chunk = blockIdx.x * 8 + grp;        // 256 chunks x 4 pairs
  float acc[15];
  #pragma unroll
  for (int k = 0; k < 15; ++k) acc[k] = 0.f;
  #pragma unroll
  for (int j = 0; j < 4; ++j) {
    const int p = chunk * 4 + j;                 // pair = u*32+v
    const int u = p >> 5, v = p & 31;
    const float wss = W_ss[p * 32 + w];
    const float wvv = W_vv[p * 32 + w];
    const float wsv = W_sv[p * 32 + w];
    const float wvs = W_vs[p * 32 + w];
    const float au = As[u], bu = Bs[u], cu = Cc[u], pu = Avv[u], qu = Bvv[u];
    const float av = As[v], bv = Bs[v], cv = Cc[v], pv = Avv[v], qv = Bvv[v];
    acc[0]  = fmaf(au * av, wss, acc[0]);
    acc[1]  = fmaf(au * bv + bu * av, wss, acc[1]);
    acc[2]  = fmaf(bu * bv, wss, acc[2]);
    acc[3]  = fmaf(au * cv + cu * av, wss, acc[3]);
    acc[4]  = fmaf(bu * cv + cu * bv, wss, acc[4]);
    acc[5]  = fmaf(cu * cv, wss, acc[5]);
    acc[6]  = fmaf(pu * pv, wvv, acc[6]);
    acc[7]  = fmaf(pu * qv + qu * pv, wvv, acc[7]);
    acc[8]  = fmaf(qu * qv, wvv, acc[8]);
    acc[9]  = fmaf(au * pv, wsv, fmaf(pu * av, wvs, acc[9]));
    acc[10] = fmaf(au * qv, wsv, fmaf(qu * av, wvs, acc[10]));
    acc[11] = fmaf(bu * pv, wsv, fmaf(pu * bv, wvs, acc[11]));
    acc[12] = fmaf(bu * qv, wsv, fmaf(qu * bv, wvs, acc[12]));
    acc[13] = fmaf(cu * pv, wsv, fmaf(pu * cv, wvs, acc[13]));
    acc[14] = fmaf(cu * qv, wsv, fmaf(qu * cv, wvs, acc[14]));
  }
  #pragma unroll
  for (int k = 0; k < 15; ++k) red[grp][k * 32 + w] = acc[k];
  __syncthreads();
  for (int kk = grp; kk < 15; kk += 8) {
    float s = 0.f;
    #pragma unroll
    for (int b = 0; b < 8; ++b) s += red[b][kk * 32 + w];
    partial[blockIdx.x * 480 + kk * 32 + w] = s;
  }
}

// ---------------- precompute 2: reduce partials, fold through Wd ------
__global__ void precompute_M(
    const float* __restrict__ Wd_s, const float* __restrict__ Wd_v,
    const float* __restrict__ partial,
    float* __restrict__ Ms, float* __restrict__ Mv)
{
  __shared__ float cf[480];
  const int t = threadIdx.x;                     // 512 threads, 1 block
  if (t < 480) {
    float s = 0.f;
    for (int b = 0; b < 32; ++b) s += partial[b * 480 + t];
    cf[t] = s;
  }
  __syncthreads();
  if (t < 128) {
    const int f = t;
    float as[9], av[6];
    #pragma unroll
    for (int k = 0; k < 9; ++k) as[k] = 0.f;
    #pragma unroll
    for (int k = 0; k < 6; ++k) av[k] = 0.f;
    for (int w = 0; w < 32; ++w) {
      const float wds = Wd_s[w * 128 + f];
      const float wdv = Wd_v[w * 128 + f];
      #pragma unroll
      for (int k = 0; k < 9; ++k) as[k] = fmaf(cf[k * 32 + w], wds, as[k]);
      #pragma unroll
      for (int k = 0; k < 6; ++k) av[k] = fmaf(cf[(9 + k) * 32 + w], wdv, av[k]);
    }
    const float sP = 1.0f / 4096.0f;                        // PW_DOWN*PW_QQ_S
    const float sQ = 0.57735026918962576451f / 4096.0f;     // *INV_SQRT3
    #pragma unroll
    for (int k = 0; k < 6; ++k) Ms[f * 16 + k] = as[k] * sP;
    #pragma unroll
    for (int k = 0; k < 3; ++k) Ms[f * 16 + 6 + k] = as[6 + k] * sQ;
    #pragma unroll
    for (int k = 0; k < 6; ++k) Mv[f * 8 + k] = av[k] * sQ;
  }
}

// ---------------- main kernel ----------------------------------------
__device__ __forceinline__ float wcomb9(const float* __restrict__ p,
    float m0, float m1, float m2, float a, float b,
    float m6, float m7, float m8)
{
  float r = p[5];
  r = fmaf(m0, p[0], r);
  r = fmaf(m1, p[1], r);
  r = fmaf(m2, p[2], r);
  r = fmaf(a,  p[3], r);
  r = fmaf(b,  p[4], r);
  r = fmaf(m6, p[6], r);
  r = fmaf(m7, p[7], r);
  r = fmaf(m8, p[8], r);
  return r;
}

// Stage one 128-row x 32-col tile (1024 float4) into buf via 8 async
// global_load_lds per wave. LDS dest is lane-contiguous; the XOR swizzle
// is applied on the GLOBAL address side: LDS element e=p*64+lane holds
// global slot (e&7)^(row&7) of row e>>3. Read side: row t, slot j at
// LDS index t*8 + (j^(t&7)) -> 2 lanes/bank-group max (free). Each wave
// stages exactly the rows its own threads later read.
__device__ __forceinline__ void stage_tile(
    const float* __restrict__ nf, float4* __restrict__ buf,
    int node0, int tl, int t)
{
  const int wv   = t >> 6;         // wave id (uniform per wave)
  const int lane = t & 63;
  const int r_in = lane >> 3;      // 0..7
  const int s_in = lane & 7;       // 0..7
  #pragma unroll
  for (int q = 0; q < 8; ++q) {
    const int p   = wv * 8 + q;
    const int row = p * 8 + r_in;
    const int gs  = s_in ^ (r_in & 7);   // row&7 == r_in
    const float4* g = reinterpret_cast<const float4*>(nf)
                    + ((size_t)(node0 + row) * 128 + tl * 8 + gs);
    gl_lds16(g, buf + p * 64);
  }
}

template<int PHASE>
__device__ __forceinline__ void vtile(
    const float4* __restrict__ cur, int t, int fb,
    const float* __restrict__ Mv,
    float g0, float g1, float g2, float d0, float d1, float d2,
    float& P, float& Q,
    float& SP0, float& SP2, float& SP4,
    float& SQ1, float& SQ3, float& SQ5)
{
  const int sw = t & 7;
  #pragma unroll
  for (int j = 0; j < 8; ++j) {
    const float4 x = cur[t * 8 + (j ^ sw)];
    const float xs[4] = {x.x, x.y, x.z, x.w};
    #pragma unroll
    for (int e = 0; e < 4; ++e) {
      const int l = 4 * j + e;
      const int i = (PHASE + l) % 3;
      const float gg = (i == 0) ? g0 : ((i == 1) ? g1 : g2);
      const float dd = (i == 0) ? d0 : ((i == 1) ? d1 : d2);
      P = fmaf(gg, xs[e], P);
      Q = fmaf(dd, xs[e], Q);
      if (i == 2) {                       // f complete -> flush
        const float* cv = Mv + (fb + (PHASE + l) / 3) * 8;  // lane-uniform
        SP0 = fmaf(cv[0], P, SP0);
        SQ1 = fmaf(cv[1], Q, SQ1);
        SP2 = fmaf(cv[2], P, SP2);
        SQ3 = fmaf(cv[3], Q, SQ3);
        SP4 = fmaf(cv[4], P, SP4);
        SQ5 = fmaf(cv[5], Q, SQ5);
        P = 0.f; Q = 0.f;
      }
    }
  }
}

__global__ __launch_bounds__(TBLK, 2) void energy_main(
    const float* __restrict__ nf,
    const float* __restrict__ ch0,
    const float* __restrict__ chi,
    const float* __restrict__ Ms,
    const float* __restrict__ Mv,
    float* __restrict__ out)
{
  __shared__ float4 buf[2][1024];         // 2 x 16 KB -> 4 blocks/CU
  const int t = threadIdx.x;
  const int node0 = blockIdx.x * TBLK;

  const float4 cc0 = reinterpret_cast<const float4*>(ch0)[node0 + t];
  const float4 cci = reinterpret_cast<const float4*>(chi)[node0 + t];

  stage_tile(nf, &buf[0][0], node0, 0, t);  // async prefetch tile 0

  const float alpha = cci.x, g0 = cci.y, g1 = cci.z, g2 = cci.w;
  const float beta  = cc0.x, d0 = cc0.y, d1 = cc0.z, d2 = cc0.w;
  const float m0 = alpha * alpha, m1 = alpha * beta, m2 = beta * beta;
  const float m6 = fmaf(g0, g0, fmaf(g1, g1, g2 * g2));
  const float m7 = fmaf(g0, d0, fmaf(g1, d1, g2 * d2));
  const float m8 = fmaf(d0, d0, fmaf(d1, d1, d2 * d2));

  const int sw = t & 7;
  float es0 = 0.f, es1 = 0.f, es2 = 0.f, es3 = 0.f;
  float P = 0.f, Q = 0.f;
  float SP0 = 0.f, SP2 = 0.f, SP4 = 0.f, SQ1 = 0.f, SQ3 = 0.f, SQ5 = 0.f;

  // Per tile: explicit full drain (all my ds_reads completed, all DMAs
  // landed) -> barrier -> issue next tile's DMA (overlaps compute) ->
  // compute current. The explicit s_waitcnt(0) is the correctness keel:
  // __syncthreads alone need not drain lgkmcnt for ds_READS (no
  // cross-wave visibility), which let R2's DMA overwrite a buffer under
  // still-in-flight reads on warm (L3-resident) replays.
  #pragma unroll
  for (int tl = 0; tl < 16; ++tl) {
    __builtin_amdgcn_s_waitcnt(0);        // vmcnt=0, expcnt=0, lgkmcnt=0
    __syncthreads();
    if (tl < 15) stage_tile(nf, &buf[(tl + 1) & 1][0], node0, tl + 1, t);
    const float4* cur = &buf[tl & 1][0];

    if (tl < 4) {                          // s-region: cols 0..127
      const float* cp0 = Ms + tl * 32 * 16;
      #pragma unroll
      for (int j = 0; j < 8; ++j) {
        const float4 x = cur[t * 8 + (j ^ sw)];
        const float* cp = cp0 + j * 64;    // lane-uniform -> s_load
        es0 = fmaf(x.x, wcomb9(cp,      m0, m1, m2, alpha, beta, m6, m7, m8), es0);
        es1 = fmaf(x.y, wcomb9(cp + 16, m0, m1, m2, alpha, beta, m6, m7, m8), es1);
        es2 = fmaf(x.z, wcomb9(cp + 32, m0, m1, m2, alpha, beta, m6, m7, m8), es2);
        es3 = fmaf(x.w, wcomb9(cp + 48, m0, m1, m2, alpha, beta, m6, m7, m8), es3);
      }
    } else {                               // v-region: cols 128..511
      const int k  = tl - 4;
      const int cb = 32 * k;               // v-col base (cc)
      const int fb = cb / 3;
      switch (cb % 3) {                    // folds to compile-time on unroll
        case 0:  vtile<0>(cur, t, fb, Mv, g0, g1, g2, d0, d1, d2, P, Q, SP0, SP2, SP4, SQ1, SQ3, SQ5); break;
        case 1:  vtile<1>(cur, t, fb, Mv, g0, g1, g2, d0, d1, d2, P, Q, SP0, SP2, SP4, SQ1, SQ3, SQ5); break;
        default: vtile<2>(cur, t, fb, Mv, g0, g1, g2, d0, d1, d2, P, Q, SP0, SP2, SP4, SQ1, SQ3, SQ5); break;
      }
    }
  }

  const float ev = fmaf(alpha, SP0 + SQ1, fmaf(beta, SP2 + SQ3, SP4 + SQ5));
  out[node0 + t] = (es0 + es1) + (es2 + es3) + ev;
}

// ---------------- launcher -------------------------------------------
extern "C" void kernel_launch(void* const* d_in, const int* in_sizes, int n_in,
                              void* d_out, int out_size, void* d_ws, size_t ws_size,
                              hipStream_t stream)
{
  const float* node_feats      = (const float*)d_in[0];
  const float* charges_0       = (const float*)d_in[1];
  const float* charges_induced = (const float*)d_in[2];
  const float* Wa_s = (const float*)d_in[8];
  const float* Wa_v = (const float*)d_in[9];
  const float* b_a  = (const float*)d_in[10];
  const float* Wb_s = (const float*)d_in[11];
  const float* Wb_v = (const float*)d_in[12];
  const float* b_b  = (const float*)d_in[13];
  const float* W_ss = (const float*)d_in[14];
  const float* W_vv = (const float*)d_in[15];
  const float* W_sv = (const float*)d_in[16];
  const float* W_vs = (const float*)d_in[17];
  const float* Wd_s = (const float*)d_in[18];
  const float* Wd_v = (const float*)d_in[19];

  float* ws      = (float*)d_ws;
  float* Ms      = ws;              // [128][16] = 2048 floats
  float* Mv      = ws + 2048;       // [128][8]  = 1024 floats
  float* partial = ws + 3072;       // [32][15][32] = 15360 floats

  precompute_coeff<<<32, 256, 0, stream>>>(Wa_s, Wa_v, b_a, Wb_s, Wb_v, b_b,
                                           W_ss, W_vv, W_sv, W_vs, partial);
  precompute_M<<<1, 512, 0, stream>>>(Wd_s, Wd_v, partial, Ms, Mv);
  energy_main<<<NNODES / TBLK, TBLK, 0, stream>>>(node_feats, charges_0,
                                                  charges_induced, Ms, Mv,
                                                  (float*)d_out);
}